// Round 1
// baseline (52.651 us; speedup 1.0000x reference)
//
#include <hip/hip_runtime.h>
#include <math.h>

#define LOG2E 1.44269504088896340736f

// lane = d + 32*kh  (d in 0..31, kh in 0..1); thread handles k = kh and kh+2.
// Block = 256 threads (4 waves); block -> (image b, row r); wave w -> cols [16w, min(62,16w+16)).
__global__ __launch_bounds__(256, 4)
void orientation_kernel(const float* __restrict__ x,
                        const float* __restrict__ Wm,
                        const float* __restrict__ qm,
                        float* __restrict__ out)
{
    const int blk  = blockIdx.x;
    const int b    = blk / 62;
    const int r    = blk - b * 62;
    const int tid  = threadIdx.x;
    const int wave = tid >> 6;
    const int lane = tid & 63;
    const int d    = lane & 31;
    const int kh   = lane >> 5;

    __shared__ float xs[3][64];
    __shared__ float red[4][4];   // [wave][k]

    // stage rows r..r+2 of image b (3*64 = 192 floats, coalesced)
    if (tid < 192) {
        const int row = tid >> 6;      // 0..2
        const int col = tid & 63;
        xs[row][col] = x[b * 4096 + (r + row) * 64 + col];
    }
    __syncthreads();

    // ---- per-thread constants for its two k values (all in VGPRs) ----
    float s0v[2][9], dsv[2][9], Wc[2][9], qc[2][9];
#pragma unroll
    for (int kk = 0; kk < 2; ++kk) {
        const int k = kh + 2 * kk;
        const int base = d * 72;
#pragma unroll
        for (int j = 0; j < 9; ++j) {
            // binary-feature synapse: value is sigmoid((x1*W - q)*10), x1 in {0,1}
            const float w0 = Wm[base + j * 4 + k];
            const float q0 = qm[base + j * 4 + k];
            const float e0 = __builtin_amdgcn_exp2f( 10.f * LOG2E * q0);          // exp(+10q)
            const float s0 = __builtin_amdgcn_rcpf(1.f + e0);                      // sigmoid(-10q)
            const float e1 = __builtin_amdgcn_exp2f(-10.f * LOG2E * (w0 - q0));    // exp(-10(W-q))
            const float s1 = __builtin_amdgcn_rcpf(1.f + e1);                      // sigmoid(10(W-q))
            s0v[kk][j] = s0;
            dsv[kk][j] = s1 - s0;
            // analog-feature synapse: e = exp(-(p*W - q)*10) = exp2(p*Wc + qc)
            const float w1 = Wm[base + (9 + j) * 4 + k];
            const float q1 = qm[base + (9 + j) * 4 + k];
            Wc[kk][j] = -10.f * LOG2E * w1;
            qc[kk][j] =  10.f * LOG2E * q1;
        }
    }

    float acc0 = 0.f, acc1 = 0.f;

    const int c0 = wave * 16;
    const int c1 = (c0 + 16 < 62) ? (c0 + 16) : 62;

    for (int c = c0; c < c1; ++c) {
        // 9 patch values (uniform-address LDS reads -> broadcast)
        float p[9];
#pragma unroll
        for (int i = 0; i < 3; ++i)
#pragma unroll
            for (int jj = 0; jj < 3; ++jj)
                p[i * 3 + jj] = xs[i][c + jj];
        const float ctr = p[4];

        float prodB0 = 1.f, prodB1 = 1.f;   // product of binary-feature sigmoids
        float prodA0 = 1.f, prodA1 = 1.f;   // product of (1 + e_j) for analog features
#pragma unroll
        for (int j = 0; j < 9; ++j) {
            const float x1f = (fabsf(p[j] - ctr) <= 3.0f) ? 1.f : 0.f;
            prodB0 *= fmaf(x1f, dsv[0][j], s0v[0][j]);
            prodB1 *= fmaf(x1f, dsv[1][j], s0v[1][j]);
            const float eA0 = __builtin_amdgcn_exp2f(fmaf(p[j], Wc[0][j], qc[0][j]));
            const float eA1 = __builtin_amdgcn_exp2f(fmaf(p[j], Wc[1][j], qc[1][j]));
            prodA0 = fmaf(prodA0, eA0, prodA0);   // prodA *= (1 + eA)
            prodA1 = fmaf(prodA1, eA1, prodA1);
        }
        float dend0 = prodB0 * __builtin_amdgcn_rcpf(prodA0);
        float dend1 = prodB1 * __builtin_amdgcn_rcpf(prodA1);

        // menb = sum over d (butterfly over lane bits 0..4; kh bit untouched)
#pragma unroll
        for (int m = 1; m <= 16; m <<= 1) {
            dend0 += __shfl_xor(dend0, m, 64);
            dend1 += __shfl_xor(dend1, m, 64);
        }

        // soma = sigmoid((menb - 0.5) * 10)
        const float soma0 = __builtin_amdgcn_rcpf(
            1.f + __builtin_amdgcn_exp2f((0.5f - dend0) * (10.f * LOG2E)));
        const float soma1 = __builtin_amdgcn_rcpf(
            1.f + __builtin_amdgcn_exp2f((0.5f - dend1) * (10.f * LOG2E)));
        acc0 += soma0;
        acc1 += soma1;
    }

    // all 32 lanes of a kh-half hold identical acc (post all-reduce); lanes 0/32 publish
    if ((lane & 31) == 0) {
        red[wave][kh]     = acc0;   // k = kh
        red[wave][kh + 2] = acc1;   // k = kh + 2
    }
    __syncthreads();

    if (tid < 4) {
        const float s = red[0][tid] + red[1][tid] + red[2][tid] + red[3][tid];
        atomicAdd(&out[b * 4 + tid], s);
    }
}

extern "C" void kernel_launch(void* const* d_in, const int* in_sizes, int n_in,
                              void* d_out, int out_size, void* d_ws, size_t ws_size,
                              hipStream_t stream) {
    const float* x  = (const float*)d_in[0];
    const float* Wm = (const float*)d_in[1];
    const float* qm = (const float*)d_in[2];
    float* out = (float*)d_out;

    const int B = in_sizes[0] / (64 * 64);   // 16

    hipMemsetAsync(d_out, 0, (size_t)out_size * sizeof(float), stream);

    dim3 grid(B * 62);
    dim3 block(256);
    orientation_kernel<<<grid, block, 0, stream>>>(x, Wm, qm, out);
}

// Round 2
// 45.353 us; speedup vs baseline: 1.1609x; 1.1609x over previous
//
#include <hip/hip_runtime.h>
#include <math.h>

#define LOG2E 1.44269504088896340736f

constexpr int IMG  = 64;        // image stride (64x64)
constexpr int OW   = 62;        // output width/height
constexpr int NPIX = 62 * 62;   // 3844 pixels per image
constexpr int D    = 32;
constexpr int K    = 4;
constexpr int CHUNKS = (NPIX + 63) / 64;   // 61 chunks of 64 pixels

// Block: 256 threads = 4 waves. wave w -> k = w, lanes -> 64 pixels of one chunk.
// menb = sum over d accumulates IN-REGISTER (no per-pixel shuffles).
// Constants (s0, ds, Wc, qc) per (k,d,j) are wave-uniform: built once per block
// into LDS, read via uniform-address ds_read_b128 (broadcast, conflict-free).
__global__ __launch_bounds__(256, 4)
void orientation_kernel(const float* __restrict__ x,
                        const float* __restrict__ Wm,
                        const float* __restrict__ qm,
                        float* __restrict__ out)
{
    __shared__ float4 tbl[K * D * 9];   // [k][d][j] = {s0, ds, Wc, qc}  (18 KB)

    const int tid = threadIdx.x;

    // ---- build transformed constant table (amortized: ~4.5 entries/thread) ----
    for (int t = tid; t < K * D * 9; t += 256) {
        // t = ((k*D + d)*9 + j)
        const int j = t % 9;
        const int dk = t / 9;
        const int d = dk % D;
        const int k = dk / D;
        const int base = d * 72;

        // binary-feature synapse: x1 in {0,1} -> value = x1 ? s1 : s0
        const float w0 = Wm[base + j * 4 + k];
        const float q0 = qm[base + j * 4 + k];
        const float s1 = __builtin_amdgcn_rcpf(
            1.f + __builtin_amdgcn_exp2f(-10.f * LOG2E * (w0 - q0)));   // sigmoid(10(W-q))
        float s0, ds;
        if (j == 4) {            // center flag forced to 1 -> always s1
            s0 = s1; ds = 0.f;
        } else {
            s0 = __builtin_amdgcn_rcpf(
                1.f + __builtin_amdgcn_exp2f(10.f * LOG2E * q0));       // sigmoid(-10q)
            ds = s1 - s0;
        }
        // analog-feature synapse: 1/(1+exp2(p*Wc + qc))
        const float w1 = Wm[base + (9 + j) * 4 + k];
        const float q1 = qm[base + (9 + j) * 4 + k];
        tbl[t] = make_float4(s0, ds, -10.f * LOG2E * w1, 10.f * LOG2E * q1);
    }
    __syncthreads();

    const int lane = tid & 63;
    const int k    = tid >> 6;            // wave id = soma index
    const int b     = blockIdx.x / CHUNKS;
    const int chunk = blockIdx.x - b * CHUNKS;

    const int pi    = chunk * 64 + lane;  // pixel index within image
    const bool valid = (pi < NPIX);
    const int pic   = valid ? pi : (NPIX - 1);
    const int row   = pic / OW;
    const int col   = pic - row * OW;

    // ---- load 3x3 patch, precompute binary flags ----
    const float* xb = x + b * IMG * IMG;
    float p[9];
#pragma unroll
    for (int i = 0; i < 3; ++i)
#pragma unroll
        for (int jj = 0; jj < 3; ++jj)
            p[i * 3 + jj] = xb[(row + i) * IMG + col + jj];

    const float ctr = p[4];
    float x1f[9];
#pragma unroll
    for (int j = 0; j < 9; ++j)
        x1f[j] = (fabsf(p[j] - ctr) <= 3.0f) ? 1.f : 0.f;

    // ---- hot loop: straight-line FMA/exp2, constants broadcast from LDS ----
    const float4* tk = &tbl[k * D * 9];
    float menb = 0.f;
#pragma unroll 2
    for (int d = 0; d < D; ++d) {
        float prodB = 1.f;   // product of binary-feature sigmoids
        float prodA = 1.f;   // product of (1 + e_j) over analog features
#pragma unroll
        for (int j = 0; j < 9; ++j) {
            const float4 c = tk[d * 9 + j];
            prodB *= fmaf(x1f[j], c.y, c.x);
            const float e = __builtin_amdgcn_exp2f(fmaf(p[j], c.z, c.w));
            prodA = fmaf(prodA, e, prodA);          // prodA *= (1 + e)
        }
        menb += prodB * __builtin_amdgcn_rcpf(prodA);
    }

    float soma = __builtin_amdgcn_rcpf(
        1.f + __builtin_amdgcn_exp2f((0.5f - menb) * (10.f * LOG2E)));
    if (!valid) soma = 0.f;

    // ---- once-per-wave reduction over the 64 pixel-lanes ----
#pragma unroll
    for (int m = 1; m <= 32; m <<= 1)
        soma += __shfl_xor(soma, m, 64);

    if (lane == 0)
        atomicAdd(&out[b * 4 + k], soma);
}

extern "C" void kernel_launch(void* const* d_in, const int* in_sizes, int n_in,
                              void* d_out, int out_size, void* d_ws, size_t ws_size,
                              hipStream_t stream) {
    const float* x  = (const float*)d_in[0];
    const float* Wm = (const float*)d_in[1];
    const float* qm = (const float*)d_in[2];
    float* out = (float*)d_out;

    const int B = in_sizes[0] / (IMG * IMG);   // 16

    hipMemsetAsync(d_out, 0, (size_t)out_size * sizeof(float), stream);

    dim3 grid(B * CHUNKS);   // 16 * 61 = 976 blocks
    dim3 block(256);
    orientation_kernel<<<grid, block, 0, stream>>>(x, Wm, qm, out);
}